// Round 3
// baseline (4183.968 us; speedup 1.0000x reference)
//
#include <hip/hip_runtime.h>

#define DIMN 4096
#define DIMB 4
#define DIMH 16
#define DIMK 64
#define DH   64

typedef __attribute__((ext_vector_type(8))) __bf16 bf16x8;
typedef __attribute__((ext_vector_type(8))) unsigned short u16x8;
typedef __attribute__((ext_vector_type(4))) float f32x4;
typedef __attribute__((ext_vector_type(4))) int i32x4;

__device__ __forceinline__ unsigned short f2bf(float f) {
  union { float f; unsigned u; } v; v.f = f;
  unsigned r = v.u + 0x7FFFu + ((v.u >> 16) & 1u);
  return (unsigned short)(r >> 16);
}
__device__ __forceinline__ float bf2f(unsigned short u) {
  union { unsigned u; float f; } v; v.u = ((unsigned)u) << 16; return v.f;
}
__device__ __forceinline__ bf16x8 ldbf8(const unsigned short* p) {
  return __builtin_bit_cast(bf16x8, *(const u16x8*)p);
}
__device__ __forceinline__ f32x4 mfma16(bf16x8 a, bf16x8 b, f32x4 c) {
  return __builtin_amdgcn_mfma_f32_16x16x32_bf16(a, b, c, 0, 0, 0);
}

// ------------- transpose + cast: src (R,C) f32 -> dst (C,R) bf16 -------------
__global__ void transpose_cast(const float* __restrict__ src, unsigned short* __restrict__ dst,
                               int R, int C) {
  __shared__ float tile[32][33];
  int c0 = blockIdx.x * 32, r0 = blockIdx.y * 32;
  for (int i = threadIdx.y; i < 32; i += 8)
    tile[i][threadIdx.x] = src[(size_t)(r0 + i) * C + c0 + threadIdx.x];
  __syncthreads();
  for (int i = threadIdx.y; i < 32; i += 8)
    dst[(size_t)(c0 + i) * R + r0 + threadIdx.x] = f2bf(tile[threadIdx.x][i]);
}

// ------------- naive fp32 qkv GEMM: C(16384x3072) = x @ W_qkv + b, scatter q/k/v bf16 -------------
__global__ __launch_bounds__(256) void gemm_qkv_naive(
    const float* __restrict__ A, const float* __restrict__ B,
    const float* __restrict__ bias,
    unsigned short* __restrict__ q, unsigned short* __restrict__ k,
    unsigned short* __restrict__ v)
{
  const int Kd = 1024, Nc = 3072;
  __shared__ float As[64][17];
  __shared__ float Bs[16][65];
  const int tid = threadIdx.x;
  const int m0 = blockIdx.x * 64, n0 = blockIdx.y * 64;
  const int lm = tid >> 2, lkc = (tid & 3) * 4;   // A staging: 64 rows x 16 k
  const int lk = tid >> 4, lnc = (tid & 15) * 4;  // B staging: 16 k x 64 cols
  const int ty = tid >> 4, tx = tid & 15;
  float acc[4][4] = {};

  for (int k0 = 0; k0 < Kd; k0 += 16) {
    float4 av = *(const float4*)&A[(size_t)(m0 + lm) * Kd + k0 + lkc];
    float4 bv = *(const float4*)&B[(size_t)(k0 + lk) * Nc + n0 + lnc];
    As[lm][lkc + 0] = av.x; As[lm][lkc + 1] = av.y;
    As[lm][lkc + 2] = av.z; As[lm][lkc + 3] = av.w;
    Bs[lk][lnc + 0] = bv.x; Bs[lk][lnc + 1] = bv.y;
    Bs[lk][lnc + 2] = bv.z; Bs[lk][lnc + 3] = bv.w;
    __syncthreads();
    #pragma unroll
    for (int kk = 0; kk < 16; ++kk) {
      float a[4], b[4];
      #pragma unroll
      for (int i = 0; i < 4; ++i) a[i] = As[ty * 4 + i][kk];
      #pragma unroll
      for (int j = 0; j < 4; ++j) b[j] = Bs[kk][tx * 4 + j];
      #pragma unroll
      for (int i = 0; i < 4; ++i)
        #pragma unroll
        for (int j = 0; j < 4; ++j)
          acc[i][j] = fmaf(a[i], b[j], acc[i][j]);
    }
    __syncthreads();
  }

  #pragma unroll
  for (int i = 0; i < 4; ++i)
    #pragma unroll
    for (int j = 0; j < 4; ++j) {
      int row = m0 + ty * 4 + i;
      int col = n0 + tx * 4 + j;
      float val = acc[i][j] + bias[col];
      int n = row >> 2, b = row & 3;           // x row-major (N,B,DIM): row = n*4+b
      int which = col >> 10, hd = col & 1023;  // 0:q 1:k 2:v
      int h = hd >> 6, d = hd & 63;
      unsigned short* dst = (which == 0) ? q : (which == 1 ? k : v);
      dst[(((size_t)(b * DIMH + h) * DIMN + n) << 6) + d] = f2bf(val);
    }
}

// ------------- naive low-rank projection (fp32 accum) -------------
// klow[bh][kk][d] = sum_n kb[bh][n][d] * E[n][kk]
__global__ __launch_bounds__(256) void proj_naive(
    const unsigned short* __restrict__ kb, const unsigned short* __restrict__ vb,
    const float* __restrict__ E, const float* __restrict__ F,
    float* __restrict__ klow, float* __restrict__ vlow)
{
  const int bh = blockIdx.x, kk = blockIdx.y, t = blockIdx.z;
  const unsigned short* src = (t ? vb : kb) + (size_t)bh * DIMN * DH;
  const float* Ew = t ? F : E;
  float* dst = (t ? vlow : klow) + ((size_t)bh * DIMK + kk) * DH;
  const int d = threadIdx.x & 63, part = threadIdx.x >> 6;

  float s = 0.f;
  for (int n = part; n < DIMN; n += 4)
    s = fmaf(bf2f(src[n * DH + d]), Ew[n * DIMK + kk], s);

  __shared__ float red[4][64];
  red[part][d] = s;
  __syncthreads();
  if (part == 0)
    dst[d] = red[0][d] + red[1][d] + red[2][d] + red[3][d];
}

// ------------- naive attention: one wave per (bh, n) row -------------
__global__ __launch_bounds__(256) void attn_naive(
    const unsigned short* __restrict__ qb, const float* __restrict__ klow,
    const float* __restrict__ vlow, unsigned short* __restrict__ ctx)
{
  const int bh = blockIdx.x, b = bh >> 4, h = bh & 15;
  const int wave = threadIdx.x >> 6, lane = threadIdx.x & 63;
  const int n = blockIdx.y * 4 + wave;
  const unsigned short* qrow = qb + ((size_t)bh * DIMN + n) * DH;
  const float* KL = klow + (size_t)bh * DIMK * DH;
  const float* VL = vlow + (size_t)bh * DIMK * DH;

  // logits: lane = kk
  float s = 0.f;
  #pragma unroll 8
  for (int d = 0; d < DH; ++d)
    s = fmaf(bf2f(qrow[d]), KL[lane * DH + d], s);
  s *= 0.125f;

  float mx = s;
  #pragma unroll
  for (int off = 1; off < 64; off <<= 1)
    mx = fmaxf(mx, __shfl_xor(mx, off, 64));
  float e = __expf(s - mx);
  float sum = e;
  #pragma unroll
  for (int off = 1; off < 64; off <<= 1)
    sum += __shfl_xor(sum, off, 64);
  float p = e / sum;

  __shared__ float Pw[4][64];
  Pw[wave][lane] = p;
  __syncthreads();

  // context: lane = d
  float o = 0.f;
  #pragma unroll 8
  for (int kk = 0; kk < DIMK; ++kk)
    o = fmaf(Pw[wave][kk], VL[kk * DH + lane], o);

  ctx[((size_t)(n * DIMB + b) << 10) + h * DH + lane] = f2bf(o);
}

// ---------------- 128x128 bf16 MFMA GEMM (final projection only) ----------------
// C(16384x1024) = ctx(bf16) @ WoutT^T + bout -> fp32 out
__global__ __launch_bounds__(256) void gemm128_out(
    const unsigned short* __restrict__ A, const unsigned short* __restrict__ Bt,
    const float* __restrict__ bias, float* __restrict__ outF)
{
  __shared__ unsigned short As[128 * 40];
  __shared__ unsigned short Bs[128 * 40];
  const int tid  = threadIdx.x;
  const int wave = tid >> 6, lane = tid & 63;
  const int quad = lane >> 4, l16 = lane & 15;
  const int wm = (wave >> 1) * 64, wn = (wave & 1) * 64;
  const int m0 = blockIdx.x * 128, n0 = blockIdx.y * 128;

  f32x4 acc[4][4] = {};

  for (int k0 = 0; k0 < 1024; k0 += 32) {
    #pragma unroll
    for (int s = 0; s < 2; ++s) {
      int idx = tid + s * 256;
      int row = idx >> 2;
      int kc  = (idx & 3) * 8;
      *(i32x4*)&As[row * 40 + kc] = *(const i32x4*)&A [(size_t)(m0 + row) * 1024 + k0 + kc];
      *(i32x4*)&Bs[row * 40 + kc] = *(const i32x4*)&Bt[(size_t)(n0 + row) * 1024 + k0 + kc];
    }
    __syncthreads();
    bf16x8 af[4], bfr[4];
    #pragma unroll
    for (int i = 0; i < 4; ++i) af[i]  = ldbf8(&As[(wm + 16 * i + l16) * 40 + quad * 8]);
    #pragma unroll
    for (int j = 0; j < 4; ++j) bfr[j] = ldbf8(&Bs[(wn + 16 * j + l16) * 40 + quad * 8]);
    #pragma unroll
    for (int i = 0; i < 4; ++i)
      #pragma unroll
      for (int j = 0; j < 4; ++j)
        acc[i][j] = mfma16(af[i], bfr[j], acc[i][j]);
    __syncthreads();
  }

  #pragma unroll
  for (int i = 0; i < 4; ++i)
    #pragma unroll
    for (int j = 0; j < 4; ++j) {
      int col = n0 + wn + 16 * j + l16;
      float bs = bias[col];
      #pragma unroll
      for (int r = 0; r < 4; ++r) {
        int row = m0 + wm + 16 * i + quad * 4 + r;
        outF[(size_t)row * 1024 + col] = acc[i][j][r] + bs;
      }
    }
}

// ---------------- launch ----------------
extern "C" void kernel_launch(void* const* d_in, const int* in_sizes, int n_in,
                              void* d_out, int out_size, void* d_ws, size_t ws_size,
                              hipStream_t stream) {
  const float* x    = (const float*)d_in[0];
  const float* E    = (const float*)d_in[1];
  const float* F    = (const float*)d_in[2];
  const float* Wqkv = (const float*)d_in[3];
  const float* bqkv = (const float*)d_in[4];
  const float* Wout = (const float*)d_in[5];
  const float* bout = (const float*)d_in[6];
  float* out = (float*)d_out;

  char* ws = (char*)d_ws;
  size_t off = 0;
  auto alloc = [&](size_t bytes) -> void* {
    void* p = ws + off; off += (bytes + 255) & ~(size_t)255; return p;
  };
  unsigned short* qb    = (unsigned short*)alloc((size_t)64 * 4096 * 64 * 2);  // 32 MB
  unsigned short* kb    = (unsigned short*)alloc((size_t)64 * 4096 * 64 * 2);  // 32 MB (ctx aliases)
  unsigned short* vb    = (unsigned short*)alloc((size_t)64 * 4096 * 64 * 2);  // 32 MB
  float*          klow  = (float*)alloc((size_t)64 * 64 * 64 * 4);             // 1 MB
  float*          vlow  = (float*)alloc((size_t)64 * 64 * 64 * 4);             // 1 MB
  unsigned short* WoutT = (unsigned short*)alloc((size_t)1024 * 1024 * 2);     // 2 MB
  unsigned short* ctx   = kb;  // kb fully consumed by proj_naive before attn writes ctx

  transpose_cast<<<dim3(32, 32), dim3(32, 8), 0, stream>>>(Wout, WoutT, 1024, 1024);
  gemm_qkv_naive<<<dim3(256, 48), dim3(256), 0, stream>>>(x, Wqkv, bqkv, qb, kb, vb);
  proj_naive<<<dim3(64, 64, 2), dim3(256), 0, stream>>>(kb, vb, E, F, klow, vlow);
  attn_naive<<<dim3(64, 1024), dim3(256), 0, stream>>>(qb, klow, vlow, ctx);
  gemm128_out<<<dim3(128, 8), dim3(256), 0, stream>>>(ctx, WoutT, bout, out);
}

// Round 7
// 627.949 us; speedup vs baseline: 6.6629x; 6.6629x over previous
//
#include <hip/hip_runtime.h>

#define DIMN 4096
#define DIMB 4
#define DIMH 16
#define DIMK 64
#define DH   64

typedef __attribute__((ext_vector_type(8))) __bf16 bf16x8;
typedef __attribute__((ext_vector_type(8))) unsigned short u16x8;
typedef __attribute__((ext_vector_type(4))) float f32x4;
typedef __attribute__((ext_vector_type(4))) int i32x4;

__device__ __forceinline__ unsigned short f2bf(float f) {
  union { float f; unsigned u; } v; v.f = f;
  unsigned r = v.u + 0x7FFFu + ((v.u >> 16) & 1u);
  return (unsigned short)(r >> 16);
}
__device__ __forceinline__ float bf2f(unsigned short u) {
  union { unsigned u; float f; } v; v.u = ((unsigned)u) << 16; return v.f;
}
// split f32 -> (hi, lo) bf16 pair: hi+lo ~ f with ~2^-17 rel error
__device__ __forceinline__ void split2(float f, unsigned short& h, unsigned short& l) {
  h = f2bf(f);
  l = f2bf(f - bf2f(h));
}
__device__ __forceinline__ bf16x8 ldbf8(const unsigned short* p) {
  return __builtin_bit_cast(bf16x8, *(const u16x8*)p);
}
__device__ __forceinline__ f32x4 mfma16(bf16x8 a, bf16x8 b, f32x4 c) {
  return __builtin_amdgcn_mfma_f32_16x16x32_bf16(a, b, c, 0, 0, 0);
}

// ------------- transpose + cast: src (R,C) f32 -> dst (C,R) bf16 [PROVEN r3] -------------
__global__ void transpose_cast(const float* __restrict__ src, unsigned short* __restrict__ dst,
                               int R, int C) {
  __shared__ float tile[32][33];
  int c0 = blockIdx.x * 32, r0 = blockIdx.y * 32;
  for (int i = threadIdx.y; i < 32; i += 8)
    tile[i][threadIdx.x] = src[(size_t)(r0 + i) * C + c0 + threadIdx.x];
  __syncthreads();
  for (int i = threadIdx.y; i < 32; i += 8)
    dst[(size_t)(c0 + i) * R + r0 + threadIdx.x] = f2bf(tile[threadIdx.x][i]);
}

// ------------- split-precision MFMA GEMM for q only -------------
// q(16384x1024) = x(f32) @ Wqkv[:, :1024](f32) + bq ; scatter q (b,h,n,d) bf16.
// A,B staged as bf16 hi+lo; acc = Ah*Bh + Ah*Bl + Al*Bh (fp32-grade result).
__global__ __launch_bounds__(256) void gemm_q_split(
    const float* __restrict__ A, const float* __restrict__ B,
    const float* __restrict__ bias, unsigned short* __restrict__ q)
{
  __shared__ unsigned short Ah[128 * 40], Al[128 * 40];
  __shared__ unsigned short Bh[128 * 40], Bl[128 * 40];
  const int tid  = threadIdx.x;
  const int wave = tid >> 6, lane = tid & 63;
  const int quad = lane >> 4, l16 = lane & 15;
  const int wm = (wave >> 1) * 64, wn = (wave & 1) * 64;
  const int m0 = blockIdx.x * 128, n0 = blockIdx.y * 128;

  f32x4 acc[4][4] = {};

  for (int k0 = 0; k0 < 1024; k0 += 32) {
    #pragma unroll
    for (int s = 0; s < 4; ++s) {
      int idx = tid + s * 256;
      int row = idx >> 3, kc = (idx & 7) * 4;
      float4 av = *(const float4*)&A[(size_t)(m0 + row) * 1024 + k0 + kc];
      ushort4 h, l;
      split2(av.x, h.x, l.x); split2(av.y, h.y, l.y);
      split2(av.z, h.z, l.z); split2(av.w, h.w, l.w);
      *(ushort4*)&Ah[row * 40 + kc] = h;
      *(ushort4*)&Al[row * 40 + kc] = l;
    }
    #pragma unroll
    for (int p = 0; p < 4; ++p) {
      int slot = tid + p * 256;
      int n_l = slot & 127, kg = slot >> 7;   // kg 0..7
      float4 bv;
      bv.x = B[(size_t)(k0 + kg * 4 + 0) * 3072 + n0 + n_l];
      bv.y = B[(size_t)(k0 + kg * 4 + 1) * 3072 + n0 + n_l];
      bv.z = B[(size_t)(k0 + kg * 4 + 2) * 3072 + n0 + n_l];
      bv.w = B[(size_t)(k0 + kg * 4 + 3) * 3072 + n0 + n_l];
      ushort4 h, l;
      split2(bv.x, h.x, l.x); split2(bv.y, h.y, l.y);
      split2(bv.z, h.z, l.z); split2(bv.w, h.w, l.w);
      *(ushort4*)&Bh[n_l * 40 + kg * 4] = h;
      *(ushort4*)&Bl[n_l * 40 + kg * 4] = l;
    }
    __syncthreads();
    bf16x8 afh[4], afl[4], bfh[4], bfl[4];
    #pragma unroll
    for (int i = 0; i < 4; ++i) {
      afh[i] = ldbf8(&Ah[(wm + 16 * i + l16) * 40 + quad * 8]);
      afl[i] = ldbf8(&Al[(wm + 16 * i + l16) * 40 + quad * 8]);
    }
    #pragma unroll
    for (int j = 0; j < 4; ++j) {
      bfh[j] = ldbf8(&Bh[(wn + 16 * j + l16) * 40 + quad * 8]);
      bfl[j] = ldbf8(&Bl[(wn + 16 * j + l16) * 40 + quad * 8]);
    }
    #pragma unroll
    for (int i = 0; i < 4; ++i)
      #pragma unroll
      for (int j = 0; j < 4; ++j) {
        acc[i][j] = mfma16(afh[i], bfh[j], acc[i][j]);
        acc[i][j] = mfma16(afh[i], bfl[j], acc[i][j]);
        acc[i][j] = mfma16(afl[i], bfh[j], acc[i][j]);
      }
    __syncthreads();
  }

  #pragma unroll
  for (int i = 0; i < 4; ++i)
    #pragma unroll
    for (int j = 0; j < 4; ++j) {
      int col = n0 + wn + 16 * j + l16;     // 0..1023 (q cols)
      float bs = bias[col];
      int h = col >> 6, d = col & 63;
      #pragma unroll
      for (int r = 0; r < 4; ++r) {
        int row = m0 + wm + 16 * i + quad * 4 + r;
        int n = row >> 2, b = row & 3;      // x row-major (N,B,DIM): row = n*4+b
        q[(((size_t)(b * DIMH + h) * DIMN + n) << 6) + d] = f2bf(acc[i][j][r] + bs);
      }
    }
}

// ------------- stage 1: partial xE/xF = E^T x, F^T x  (all fp32) -------------
// partial[ns][kk128][b][dim1024] ; grid 512 = (ns8, b4, cg4, kkg4); 256 thr = dims
__global__ __launch_bounds__(256) void reduce_xEF1(
    const float* __restrict__ x, const float* __restrict__ E, const float* __restrict__ F,
    float* __restrict__ partial)
{
  const int bid = blockIdx.x;
  const int ns = bid >> 6, b = (bid >> 4) & 3, cg = (bid >> 2) & 3, kkg = bid & 3;
  const float* Ew = (kkg < 2) ? E : F;
  const int kc0 = (kkg & 1) * 32;
  const int dim = cg * 256 + threadIdx.x;

  float acc[32];
  #pragma unroll
  for (int i = 0; i < 32; ++i) acc[i] = 0.f;

  const int nlo = ns * 512, nhi = nlo + 512;
  for (int n = nlo; n < nhi; ++n) {
    float xv = x[((size_t)n * 4 + b) * 1024 + dim];
    #pragma unroll
    for (int i = 0; i < 32; ++i)
      acc[i] = fmaf(Ew[n * 64 + kc0 + i], xv, acc[i]);
  }
  #pragma unroll
  for (int i = 0; i < 32; ++i) {
    int kk = kkg * 32 + i;   // 0..127 (E: 0..63, F: 64..127)
    partial[(((size_t)ns * 128 + kk) * 4 + b) * 1024 + dim] = acc[i];
  }
}

// ------------- stage 2: xEF[kk128][b][dim] = sum_ns partial -------------
__global__ __launch_bounds__(256) void reduce_xEF2(
    const float* __restrict__ partial, float* __restrict__ xEF)
{
  int t = blockIdx.x * 256 + threadIdx.x;   // 0..524287 = kk*4096 + b*1024 + dim
  float s = 0.f;
  #pragma unroll
  for (int ns = 0; ns < 8; ++ns)
    s += partial[(size_t)ns * 524288 + t];
  xEF[t] = s;
}

// ------------- column sums of E and F: sEF[kk] (kk<64: E, else F) -------------
__global__ void colsum_EF(const float* __restrict__ E, const float* __restrict__ F,
                          float* __restrict__ sEF) {
  const float* src = blockIdx.x ? F : E;
  int kk = threadIdx.x;   // 0..63
  float s = 0.f;
  for (int n = 0; n < DIMN; n += 8) {
    #pragma unroll
    for (int e = 0; e < 8; ++e)
      s += src[(n + e) * 64 + kk];
  }
  sEF[blockIdx.x * 64 + kk] = s;
}

// ------------- klow/vlow (fp32): C(64kk x 1024col) = xE_b @ Wqkv[:,1024(1+t)+col] -------------
// + sE[kk]*bias.  Output layout klow[bh][kk][d], fp32.  [r3-naive tile structure]
__global__ __launch_bounds__(256) void proj_klv(
    const float* __restrict__ xEF, const float* __restrict__ W,
    const float* __restrict__ bias, const float* __restrict__ sEF,
    float* __restrict__ klow, float* __restrict__ vlow)
{
  __shared__ float As[64][17];
  __shared__ float Bs[16][65];
  const int tid = threadIdx.x;
  const int nt = blockIdx.x, b = blockIdx.y, t = blockIdx.z;
  const int colbase = 1024 * (1 + t) + nt * 64;
  const float* Ap = xEF + (size_t)t * 64 * 4096;   // rows kk: xEF[(t*64+kk)*4 + b)*1024 + dim]
  float* dstb = (t ? vlow : klow);
  const int lm = tid >> 2, lkc = (tid & 3) * 4;
  const int lk = tid >> 4, lnc = (tid & 15) * 4;
  const int ty = tid >> 4, tx = tid & 15;
  float acc[4][4] = {};

  for (int k0 = 0; k0 < 1024; k0 += 16) {
    float4 av = *(const float4*)&Ap[((size_t)lm * 4 + b) * 1024 + k0 + lkc];
    float4 bv = *(const float4*)&W[(size_t)(k0 + lk) * 3072 + colbase + lnc];
    As[lm][lkc + 0] = av.x; As[lm][lkc + 1] = av.y;
    As[lm][lkc + 2] = av.z; As[lm][lkc + 3] = av.w;
    Bs[lk][lnc + 0] = bv.x; Bs[lk][lnc + 1] = bv.y;
    Bs[lk][lnc + 2] = bv.z; Bs[lk][lnc + 3] = bv.w;
    __syncthreads();
    #pragma unroll
    for (int kk = 0; kk < 16; ++kk) {
      float a[4], bb[4];
      #pragma unroll
      for (int i = 0; i < 4; ++i) a[i] = As[ty * 4 + i][kk];
      #pragma unroll
      for (int j = 0; j < 4; ++j) bb[j] = Bs[kk][tx * 4 + j];
      #pragma unroll
      for (int i = 0; i < 4; ++i)
        #pragma unroll
        for (int j = 0; j < 4; ++j)
          acc[i][j] = fmaf(a[i], bb[j], acc[i][j]);
    }
    __syncthreads();
  }

  #pragma unroll
  for (int i = 0; i < 4; ++i) {
    int kk = ty * 4 + i;
    float se = sEF[t * 64 + kk];
    #pragma unroll
    for (int j = 0; j < 4; ++j) {
      int c = nt * 64 + tx * 4 + j;          // 0..1023
      int h = c >> 6, d = c & 63;
      float val = acc[i][j] + se * bias[1024 * (1 + t) + c];
      dstb[(((size_t)b * DIMH + h) * DIMK + kk) * DH + d] = val;
    }
  }
}

// ------------- fused dots -> softmax -> PV -------------
// KL/VL fp32; K and V split hi/lo bf16 for MFMA (near-fp32 logits & PV).
__global__ __launch_bounds__(256) void attn_fused(
    const unsigned short* __restrict__ qb, const float* __restrict__ klow,
    const float* __restrict__ vlow, unsigned short* __restrict__ ctx)
{
  __shared__ unsigned short VTh[64][72], VTl[64][72];  // [d][k], k<72
  __shared__ unsigned short Plds[4][32][72];
  const int bh = blockIdx.x, b = bh >> 4, h = bh & 15;
  const unsigned short* Q  = qb   + (size_t)bh * DIMN * DH;
  const float* KL = klow + (size_t)bh * DIMK * DH;
  const float* VL = vlow + (size_t)bh * DIMK * DH;
  const int tid = threadIdx.x, wave = tid >> 6, lane = tid & 63;
  const int quad = lane >> 4, l16 = lane & 15;

  #pragma unroll
  for (int it = 0; it < 2; ++it) {
    int idx = tid + it * 256;
    int kk = idx >> 3, d0 = (idx & 7) * 8;
    float4 f0 = *(const float4*)&VL[kk * DH + d0];
    float4 f1 = *(const float4*)&VL[kk * DH + d0 + 4];
    float vv[8] = {f0.x, f0.y, f0.z, f0.w, f1.x, f1.y, f1.z, f1.w};
    #pragma unroll
    for (int e = 0; e < 8; ++e) {
      unsigned short hh, ll;
      split2(vv[e], hh, ll);
      VTh[d0 + e][kk] = hh;
      VTl[d0 + e][kk] = ll;
    }
  }
  bf16x8 kfh[2][4], kfl[2][4];
  #pragma unroll
  for (int dc = 0; dc < 2; ++dc)
    #pragma unroll
    for (int j = 0; j < 4; ++j) {
      const float* p = &KL[(j * 16 + l16) * DH + dc * 32 + quad * 8];
      float4 f0 = *(const float4*)p;
      float4 f1 = *(const float4*)(p + 4);
      float vv[8] = {f0.x, f0.y, f0.z, f0.w, f1.x, f1.y, f1.z, f1.w};
      alignas(16) unsigned short th[8], tl[8];
      #pragma unroll
      for (int e = 0; e < 8; ++e) split2(vv[e], th[e], tl[e]);
      kfh[dc][j] = ldbf8(th);
      kfl[dc][j] = ldbf8(tl);
    }
  __syncthreads();

  const int n_base = blockIdx.y * 128 + wave * 32;

  f32x4 sacc[2][4] = {};
  #pragma unroll
  for (int rt = 0; rt < 2; ++rt)
    #pragma unroll
    for (int dc = 0; dc < 2; ++dc) {
      bf16x8 a = ldbf8(&Q[(size_t)(n_base + rt * 16 + l16) * DH + dc * 32 + quad * 8]);
      #pragma unroll
      for (int j = 0; j < 4; ++j) {
        sacc[rt][j] = mfma16(a, kfh[dc][j], sacc[rt][j]);
        sacc[rt][j] = mfma16(a, kfl[dc][j], sacc[rt][j]);
      }
    }

  const float scale = 0.125f;
  #pragma unroll
  for (int rt = 0; rt < 2; ++rt)
    #pragma unroll
    for (int r = 0; r < 4; ++r) {
      float v0 = sacc[rt][0][r] * scale, v1 = sacc[rt][1][r] * scale;
      float v2 = sacc[rt][2][r] * scale, v3 = sacc[rt][3][r] * scale;
      float mx = fmaxf(fmaxf(v0, v1), fmaxf(v2, v3));
      #pragma unroll
      for (int off = 1; off < 16; off <<= 1)
        mx = fmaxf(mx, __shfl_xor(mx, off, 64));
      float e0 = __expf(v0 - mx), e1 = __expf(v1 - mx);
      float e2 = __expf(v2 - mx), e3 = __expf(v3 - mx);
      float sm = e0 + e1 + e2 + e3;
      #pragma unroll
      for (int off = 1; off < 16; off <<= 1)
        sm += __shfl_xor(sm, off, 64);
      float inv = 1.0f / sm;
      int prow = rt * 16 + quad * 4 + r;
      Plds[wave][prow][ 0 + l16] = f2bf(e0 * inv);
      Plds[wave][prow][16 + l16] = f2bf(e1 * inv);
      Plds[wave][prow][32 + l16] = f2bf(e2 * inv);
      Plds[wave][prow][48 + l16] = f2bf(e3 * inv);
    }
  __syncthreads();

  f32x4 oacc[2][4] = {};
  #pragma unroll
  for (int rt = 0; rt < 2; ++rt)
    #pragma unroll
    for (int kc = 0; kc < 2; ++kc) {
      bf16x8 a = ldbf8(&Plds[wave][rt * 16 + l16][kc * 32 + quad * 8]);
      #pragma unroll
      for (int j = 0; j < 4; ++j) {
        bf16x8 bh_ = ldbf8(&VTh[j * 16 + l16][kc * 32 + quad * 8]);
        bf16x8 bl_ = ldbf8(&VTl[j * 16 + l16][kc * 32 + quad * 8]);
        oacc[rt][j] = mfma16(a, bh_, oacc[rt][j]);
        oacc[rt][j] = mfma16(a, bl_, oacc[rt][j]);
      }
    }

  #pragma unroll
  for (int rt = 0; rt < 2; ++rt)
    #pragma unroll
    for (int j = 0; j < 4; ++j)
      #pragma unroll
      for (int r = 0; r < 4; ++r) {
        int n = n_base + rt * 16 + quad * 4 + r;
        ctx[((size_t)(n * DIMB + b) << 10) + h * DH + j * 16 + l16] = f2bf(oacc[rt][j][r]);
      }
}

// ---------------- 128x128 bf16 MFMA GEMM (final projection) [PROVEN r3 verbatim] ----------------
__global__ __launch_bounds__(256) void gemm128_out(
    const unsigned short* __restrict__ A, const unsigned short* __restrict__ Bt,
    const float* __restrict__ bias, float* __restrict__ outF)
{
  __shared__ unsigned short As[128 * 40];
  __shared__ unsigned short Bs[128 * 40];
  const int tid  = threadIdx.x;
  const int wave = tid >> 6, lane = tid & 63;
  const int quad = lane >> 4, l16 = lane & 15;
  const int wm = (wave >> 1) * 64, wn = (wave & 1) * 64;
  const int m0 = blockIdx.x * 128, n0 = blockIdx.y * 128;

  f32x4 acc[4][4] = {};

  for (int k0 = 0; k0 < 1024; k0 += 32) {
    #pragma unroll
    for (int s = 0; s < 2; ++s) {
      int idx = tid + s * 256;
      int row = idx >> 2;
      int kc  = (idx & 3) * 8;
      *(i32x4*)&As[row * 40 + kc] = *(const i32x4*)&A [(size_t)(m0 + row) * 1024 + k0 + kc];
      *(i32x4*)&Bs[row * 40 + kc] = *(const i32x4*)&Bt[(size_t)(n0 + row) * 1024 + k0 + kc];
    }
    __syncthreads();
    bf16x8 af[4], bfr[4];
    #pragma unroll
    for (int i = 0; i < 4; ++i) af[i]  = ldbf8(&As[(wm + 16 * i + l16) * 40 + quad * 8]);
    #pragma unroll
    for (int j = 0; j < 4; ++j) bfr[j] = ldbf8(&Bs[(wn + 16 * j + l16) * 40 + quad * 8]);
    #pragma unroll
    for (int i = 0; i < 4; ++i)
      #pragma unroll
      for (int j = 0; j < 4; ++j)
        acc[i][j] = mfma16(af[i], bfr[j], acc[i][j]);
    __syncthreads();
  }

  #pragma unroll
  for (int i = 0; i < 4; ++i)
    #pragma unroll
    for (int j = 0; j < 4; ++j) {
      int col = n0 + wn + 16 * j + l16;
      float bs = bias[col];
      #pragma unroll
      for (int r = 0; r < 4; ++r) {
        int row = m0 + wm + 16 * i + quad * 4 + r;
        outF[(size_t)row * 1024 + col] = acc[i][j][r] + bs;
      }
    }
}

// ---------------- launch ----------------
extern "C" void kernel_launch(void* const* d_in, const int* in_sizes, int n_in,
                              void* d_out, int out_size, void* d_ws, size_t ws_size,
                              hipStream_t stream) {
  const float* x    = (const float*)d_in[0];
  const float* E    = (const float*)d_in[1];
  const float* F    = (const float*)d_in[2];
  const float* Wqkv = (const float*)d_in[3];
  const float* bqkv = (const float*)d_in[4];
  const float* Wout = (const float*)d_in[5];
  const float* bout = (const float*)d_in[6];
  float* out = (float*)d_out;

  char* ws = (char*)d_ws;
  size_t off = 0;
  auto alloc = [&](size_t bytes) -> void* {
    void* p = ws + off; off += (bytes + 255) & ~(size_t)255; return p;
  };
  // total ~86 MB (< r3-proven 100 MB)
  unsigned short* qb    = (unsigned short*)alloc((size_t)64 * 4096 * 64 * 2);   // 32 MB
  unsigned short* ctx   = (unsigned short*)alloc((size_t)16384 * 1024 * 2);     // 32 MB
  float*          part  = (float*)alloc((size_t)8 * 128 * 4 * 1024 * 4);        // 16 MB
  float*          xEF   = (float*)alloc((size_t)128 * 4 * 1024 * 4);            // 2 MB
  float*          sEF   = (float*)alloc(128 * 4);                               // 512 B
  float*          klow  = (float*)alloc((size_t)64 * 64 * 64 * 4);              // 1 MB
  float*          vlow  = (float*)alloc((size_t)64 * 64 * 64 * 4);              // 1 MB
  unsigned short* WoutT = (unsigned short*)alloc((size_t)1024 * 1024 * 2);      // 2 MB

  transpose_cast<<<dim3(32, 32), dim3(32, 8), 0, stream>>>(Wout, WoutT, 1024, 1024);
  gemm_q_split<<<dim3(128, 8), dim3(256), 0, stream>>>(x, Wqkv, bqkv, qb);
  reduce_xEF1<<<dim3(512), dim3(256), 0, stream>>>(x, E, F, part);
  reduce_xEF2<<<dim3(2048), dim3(256), 0, stream>>>(part, xEF);
  colsum_EF<<<dim3(2), dim3(64), 0, stream>>>(E, F, sEF);
  proj_klv<<<dim3(16, 4, 2), dim3(256), 0, stream>>>(xEF, Wqkv, bqkv, sEF, klow, vlow);
  attn_fused<<<dim3(64, 32), dim3(256), 0, stream>>>(qb, klow, vlow, ctx);
  gemm128_out<<<dim3(128, 8), dim3(256), 0, stream>>>(ctx, WoutT, bout, out);
}